// Round 7
// baseline (11238.403 us; speedup 1.0000x reference)
//
#include <hip/hip_runtime.h>

#define NSTEP 512
#define EDIM  512
#define REC   2048
#define NB    64
#define KSEL  819
#define KC    8       // K chunks of 256 (kc = bid & 7 -> XCD-local)
#define ZCH   256     // K per block
#define AP    264     // padded k-stride (u16) for LDS tiles
#define CSTR  16896   // 64*AP: component stride inside LDS tiles
#define SLOTU 262144  // u16 per r-slot (2 comps x 64 x 2048)

typedef unsigned short u16;
typedef __bf16 bf16x8 __attribute__((ext_vector_type(8)));
typedef float  f32x4  __attribute__((ext_vector_type(4)));
typedef unsigned long long ull;

static __device__ __forceinline__ f32x4 mfma16(bf16x8 a, bf16x8 b, f32x4 c) {
    return __builtin_amdgcn_mfma_f32_16x16x32_bf16(a, b, c, 0, 0, 0);
}

// fp32 -> 2 bf16 components (hi, lo): ~17 mantissa bits
static __device__ __forceinline__ void split2(float v, u16& c0, u16& c1) {
    __bf16 b0 = (__bf16)v;
    __bf16 b1 = (__bf16)(v - (float)b0);
    c0 = __builtin_bit_cast(u16, b0);
    c1 = __builtin_bit_cast(u16, b1);
}

// ---- agent-scope (sc1) coherent helpers — compiler-tracked (NO inline asm,
// ---- r6 lesson), drained by __syncthreads before barrier arrive ----
static __device__ __forceinline__ void cstore8u(void* p, ull v) {
    __hip_atomic_store((ull*)p, v, __ATOMIC_RELAXED, __HIP_MEMORY_SCOPE_AGENT);
}
static __device__ __forceinline__ void cstore8f(float* p, float a, float b) {
    float2 v = make_float2(a, b);
    ull u; __builtin_memcpy(&u, &v, 8);
    __hip_atomic_store((ull*)p, u, __ATOMIC_RELAXED, __HIP_MEMORY_SCOPE_AGENT);
}
static __device__ __forceinline__ ull cload8u(const void* p) {
    return __hip_atomic_load((const ull*)p, __ATOMIC_RELAXED, __HIP_MEMORY_SCOPE_AGENT);
}
static __device__ __forceinline__ float2 cload8f(const float* p) {
    ull u = cload8u(p);
    float2 v; __builtin_memcpy(&v, &u, 8);
    return v;
}

// ---- two-level grid barrier (r3/r4/r5-proven, no fences) ----
__device__ __forceinline__ void gbar(unsigned* bar, int bid, unsigned gen)
{
    __syncthreads();
    if (threadIdx.x == 0) {
        const int g = bid >> 4;
        unsigned v = __hip_atomic_fetch_add(&bar[g * 32], 1u,
                        __ATOMIC_RELAXED, __HIP_MEMORY_SCOPE_AGENT);
        if (v + 1u == gen * 16u)
            __hip_atomic_fetch_add(&bar[1024], 1u,
                        __ATOMIC_RELAXED, __HIP_MEMORY_SCOPE_AGENT);
        while (__hip_atomic_load(&bar[1024], __ATOMIC_RELAXED,
                        __HIP_MEMORY_SCOPE_AGENT) < gen * 16u)
            __builtin_amdgcn_s_sleep(1);
        __asm__ volatile("" ::: "memory");
    }
    __syncthreads();
}

// ---------------------------------------------------------------------------
// Persistent kernel: 256 blocks x 512 threads.
// Block: kc = bid&7 (same k-slice -> same XCD, L2-dedup'd r reads),
//        nc = bid>>3 (64 cols).
// r state: rotated write-once slots (rot=1) read with NORMAL cached loads;
//          fallback rot=0 = r5 sc1 protocol.
// LDS (151552 B): WrSu 67584 | aSu 67584 | zS 16384. Update scratch aliases
// aSu; Y-precompute WiP/xP alias WrSu.
// ---------------------------------------------------------------------------
__global__ __launch_bounds__(512, 1)
void rnn_persistent(const float* __restrict__ x, const float* __restrict__ Wi,
                    const float* __restrict__ Wr, float* __restrict__ out,
                    u16* __restrict__ rTu, float* __restrict__ zpart,
                    u16* __restrict__ Ybf, unsigned* __restrict__ bar, int rot)
{
    extern __shared__ __align__(16) char smem[];
    u16* WrSu = (u16*)smem;                         // + c*CSTR
    u16* aSu  = (u16*)(smem + 67584);               // + c*CSTR
    float* zS = (float*)(smem + 135168);            // [64][64] f32 bounce
    // Y-precompute views (alias WrS region)
    float* WiP = (float*)smem;                      // [32][128] 16 KB
    float* xP  = (float*)(smem + 16384);            // [32][64]   8 KB
    // update-phase views (alias aS region)
    unsigned*      kS   = (unsigned*)(smem + 67584);          // [2048] 8 KB
    unsigned char* selS = (unsigned char*)(smem + 67584 + 8192);
    unsigned*      hist = (unsigned*)(smem + 67584 + 10240);
    unsigned*      scn  = (unsigned*)(smem + 67584 + 11264);
    __shared__ unsigned s_byte, s_newrem;
    __shared__ float red[8];
    __shared__ float s_norm;

    const int bid = blockIdx.x;
    const int tid = threadIdx.x;
    const int kc = bid & 7, nc = bid >> 3;
    const int n0 = nc * 64, kcbase = kc * ZCH;
    const int wid = tid >> 6, lane = tid & 63;
    const int q = lane >> 4, l16 = lane & 15;
    const int Moff = (wid & 3) * 16, Npair = wid >> 2;
    unsigned gen = 0;

    // ================= Y precompute: Y[t][b][j] = (x_t @ Wi) bf16 ===========
    {
        const int t0 = bid * 2;
        const int tr4 = (tid >> 5) * 4;
        const int tc4 = (tid & 31) * 4;
        for (int nc2 = 0; nc2 < 16; ++nc2) {
            const int n0y = nc2 * 128;
            f32x4 acc[2][4];
#pragma unroll
            for (int h = 0; h < 2; ++h)
#pragma unroll
                for (int i = 0; i < 4; ++i) acc[h][i] = (f32x4){0,0,0,0};
            for (int kr = 0; kr < 16; ++kr) {
                const int k0y = kr * 32;
                __syncthreads();
                {
                    const int col4 = (tid & 31) * 4, row = tid >> 5;
                    *(float4*)&WiP[row * 128 + col4] =
                        *(const float4*)(Wi + (long long)(k0y + row) * REC + n0y + col4);
                    *(float4*)&WiP[(row + 16) * 128 + col4] =
                        *(const float4*)(Wi + (long long)(k0y + row + 16) * REC + n0y + col4);
                }
                for (int h = 0; h < 2; ++h) {
                    __syncthreads();
                    {
                        const int b = tid & 63, e4 = (tid >> 6) * 4;
                        const float4 v = *(const float4*)(x + ((long long)b * NSTEP + (t0 + h)) * EDIM + k0y + e4);
                        xP[(e4    ) * 64 + b] = v.x;
                        xP[(e4 + 1) * 64 + b] = v.y;
                        xP[(e4 + 2) * 64 + b] = v.z;
                        xP[(e4 + 3) * 64 + b] = v.w;
                    }
                    __syncthreads();
#pragma unroll 8
                    for (int kk = 0; kk < 32; ++kk) {
                        const float4 af = *(const float4*)&xP[kk * 64 + tr4];
                        const float4 bf = *(const float4*)&WiP[kk * 128 + tc4];
                        const float av[4] = {af.x, af.y, af.z, af.w};
#pragma unroll
                        for (int i = 0; i < 4; ++i) {
                            acc[h][i].x += av[i] * bf.x;
                            acc[h][i].y += av[i] * bf.y;
                            acc[h][i].z += av[i] * bf.z;
                            acc[h][i].w += av[i] * bf.w;
                        }
                    }
                }
            }
#pragma unroll
            for (int h = 0; h < 2; ++h)
#pragma unroll
                for (int i = 0; i < 4; ++i) {
                    const long long yrow = (long long)(t0 + h) * 64 + tr4 + i;
                    u16 o[4];
                    o[0] = __builtin_bit_cast(u16, (__bf16)acc[h][i].x);
                    o[1] = __builtin_bit_cast(u16, (__bf16)acc[h][i].y);
                    o[2] = __builtin_bit_cast(u16, (__bf16)acc[h][i].z);
                    o[3] = __builtin_bit_cast(u16, (__bf16)acc[h][i].w);
                    ull pk; __builtin_memcpy(&pk, o, 8);
                    cstore8u(&Ybf[yrow * REC + n0y + tc4], pk);
                }
        }
    }
    // ---- zero r slot 0 (2 comps x 64 x 2048 bf16 = 65536 8-B chunks) ----
    {
        const int g = bid * 512 + tid;
        if (g < 65536) cstore8u(rTu + (long long)g * 4, 0ull);
    }
    ++gen; gbar(bar, bid, gen);

    // ================= one-time: stage + split Wr tile into LDS =============
    {
        for (int it = 0; it < 32; ++it) {
            const int row = it * 8 + wid;       // k index within slice
            const int col = lane;               // n index
            const float v = Wr[(long long)(kcbase + row) * REC + n0 + col];
            u16 s0, s1; split2(v, s0, s1);
            const int base = col * AP + row;
            WrSu[base] = s0;
            WrSu[CSTR + base] = s1;
        }
        __syncthreads();
    }

    // ================= main recurrence ======================================
    const int hw = tid >> 5, hl = tid & 31;
    for (int t = 0; t < NSTEP; ++t) {
        // ---- stage aS: 2 comps x 64 b x 256 k ----
        if (rot) {
            // write-once slot t: NORMAL cached 16B loads (L2-dedup'd per XCD)
            const u16* slot = rTu + (long long)t * SLOTU;
            float4 va[8];
#pragma unroll
            for (int i = 0; i < 8; ++i) {
                const int c = i >> 2;
                const int b = (i & 3) * 16 + hw;
                va[i] = *(const float4*)(slot + (long long)c * 131072 + (long long)b * REC + kcbase + hl * 8);
            }
#pragma unroll
            for (int i = 0; i < 8; ++i) {
                const int c = i >> 2;
                const int b = (i & 3) * 16 + hw;
                *(float4*)(aSu + c * CSTR + b * AP + hl * 8) = va[i];
            }
        } else {
            // fallback: r5 sc1 8B staging
            ull va[8], vb[8];
#pragma unroll
            for (int i = 0; i < 8; ++i) {
                const int c = i >> 2;
                const int b = (i & 3) * 16 + hw;
                const u16* src = rTu + (long long)c * 131072 + (long long)b * REC + kcbase + hl * 8;
                va[i] = cload8u(src);
                vb[i] = cload8u(src + 4);
            }
#pragma unroll
            for (int i = 0; i < 8; ++i) {
                const int c = i >> 2;
                const int b = (i & 3) * 16 + hw;
                u16* dst = aSu + c * CSTR + b * AP + hl * 8;
                *(ull*)dst = va[i];
                *(ull*)(dst + 4) = vb[i];
            }
        }
        __syncthreads();

        // ---- z partial: 3-pass split-bf16 MFMA, K=256 ----
        f32x4 acc0 = {0,0,0,0}, acc1 = {0,0,0,0};
#pragma unroll
        for (int ks = 0; ks < 8; ++ks) {
            const int kk = ks * 32 + q * 8;
            const u16* ap = aSu + (Moff + l16) * AP + kk;
            bf16x8 A0 = *(const bf16x8*)(ap);
            bf16x8 A1 = *(const bf16x8*)(ap + CSTR);
            const u16* bp0 = WrSu + (Npair * 32 + l16) * AP + kk;
            bf16x8 B00 = *(const bf16x8*)(bp0);
            bf16x8 B01 = *(const bf16x8*)(bp0 + CSTR);
            const u16* bp1 = bp0 + 16 * AP;
            bf16x8 B10 = *(const bf16x8*)(bp1);
            bf16x8 B11 = *(const bf16x8*)(bp1 + CSTR);
            acc0 = mfma16(A0, B00, acc0);
            acc1 = mfma16(A0, B10, acc1);
            acc0 = mfma16(A0, B01, acc0);
            acc1 = mfma16(A0, B11, acc1);
            acc0 = mfma16(A1, B00, acc0);
            acc1 = mfma16(A1, B10, acc1);
        }
        // ---- bounce D-frags through zS, then paired 8B sc1 stores ----
        {
#pragma unroll
            for (int i = 0; i < 4; ++i) {
                zS[(Moff + q * 4 + i) * 64 + Npair * 32 + l16]      = ((float*)&acc0)[i];
                zS[(Moff + q * 4 + i) * 64 + Npair * 32 + l16 + 16] = ((float*)&acc1)[i];
            }
            __syncthreads();
            const int row = tid >> 3, seg = (tid & 7) * 8;
            float* zp = zpart + (long long)(kc * 64 + row) * REC + n0 + seg;
#pragma unroll
            for (int i = 0; i < 4; ++i)
                cstore8f(zp + i * 2, zS[row * 64 + seg + i * 2], zS[row * 64 + seg + i * 2 + 1]);
        }
        ++gen; gbar(bar, bid, gen);   // partials visible

        // ---- phase B: blocks 0..63 (uniform across XCDs), row = bid ----
        if (bid < NB) {
            const int b = bid;
            const int j0 = tid * 4;
            float zs[4] = {0,0,0,0};
#pragma unroll
            for (int k2 = 0; k2 < KC; ++k2) {
                const long long base = ((long long)(k2 * 64) + b) * REC + j0;
                float2 u0 = cload8f(zpart + base);
                float2 u1 = cload8f(zpart + base + 2);
                zs[0] += u0.x; zs[1] += u0.y; zs[2] += u1.x; zs[3] += u1.y;
            }
            {
                uint4 kv; unsigned u;
                u = __float_as_uint(zs[0]); kv.x = (u & 0x80000000u) ? ~u : (u | 0x80000000u);
                u = __float_as_uint(zs[1]); kv.y = (u & 0x80000000u) ? ~u : (u | 0x80000000u);
                u = __float_as_uint(zs[2]); kv.z = (u & 0x80000000u) ? ~u : (u | 0x80000000u);
                u = __float_as_uint(zs[3]); kv.w = (u & 0x80000000u) ? ~u : (u | 0x80000000u);
                *(uint4*)&kS[j0] = kv;
            }
            __syncthreads();
            unsigned prefix = 0, remaining = KSEL;
            for (int byte = 3; byte >= 0; --byte) {
                if (tid < 256) hist[tid] = 0u;
                __syncthreads();
                const int shift = byte * 8;
                const unsigned pmask = (byte == 3) ? 0u : (0xFFFFFFFFu << (shift + 8));
#pragma unroll
                for (int s = 0; s < 4; ++s) {
                    const unsigned key = kS[j0 + s];
                    if ((key & pmask) == prefix)
                        atomicAdd(&hist[(key >> shift) & 255u], 1u);
                }
                __syncthreads();
                if (tid < 64) {
                    const unsigned h0 = hist[tid * 4 + 0];
                    const unsigned h1 = hist[tid * 4 + 1];
                    const unsigned h2 = hist[tid * 4 + 2];
                    const unsigned h3 = hist[tid * 4 + 3];
                    const unsigned tot = h0 + h1 + h2 + h3;
                    unsigned suf = tot;
#pragma unroll
                    for (int st = 1; st < 64; st <<= 1) {
                        unsigned o = __shfl_down(suf, (unsigned)st);
                        if (tid + st >= 64) o = 0u;
                        suf += o;
                    }
                    unsigned S[5];
                    S[0] = suf; S[1] = suf - h0; S[2] = suf - h0 - h1;
                    S[3] = suf - h0 - h1 - h2; S[4] = suf - tot;
#pragma unroll
                    for (int qq = 0; qq < 4; ++qq) {
                        if (S[qq] >= remaining && S[qq + 1] < remaining) {
                            s_byte = (unsigned)(tid * 4 + qq);
                            s_newrem = remaining - S[qq + 1];
                        }
                    }
                }
                __syncthreads();
                prefix |= (s_byte << shift);
                remaining = s_newrem;
                __syncthreads();
            }
            const unsigned T = prefix;
            const unsigned need = remaining;
            const unsigned cnteq = hist[T & 255u];
            if (need == cnteq) {
#pragma unroll
                for (int s = 0; s < 4; ++s)
                    selS[j0 + s] = (kS[j0 + s] >= T) ? 1 : 0;
                __syncthreads();
            } else {
                int c = 0; unsigned char eqv[4];
#pragma unroll
                for (int s = 0; s < 4; ++s) { eqv[s] = (kS[j0 + s] == T) ? 1 : 0; c += eqv[s]; }
                scn[tid] = (unsigned)c; __syncthreads();
                for (int st = 1; st < 512; st <<= 1) {
                    unsigned v2 = (tid >= st) ? scn[tid - st] : 0u;
                    __syncthreads();
                    scn[tid] += v2;
                    __syncthreads();
                }
                unsigned p = scn[tid] - (unsigned)c;
#pragma unroll
                for (int s = 0; s < 4; ++s) {
                    unsigned char sel;
                    if (eqv[s]) { sel = (p < need) ? 1 : 0; ++p; }
                    else        { sel = (kS[j0 + s] > T) ? 1 : 0; }
                    selS[j0 + s] = sel;
                }
                __syncthreads();
            }
            // r_new = tanh(y + masked z), row-normalize
            float rn[4]; float ss = 0.f;
            {
                const ushort4 yv = *(const ushort4*)&Ybf[((long long)t * 64 + b) * REC + j0];
                const u16 ya[4] = {yv.x, yv.y, yv.z, yv.w};
#pragma unroll
                for (int s = 0; s < 4; ++s) {
                    const float y = __uint_as_float(((unsigned)ya[s]) << 16);
                    const float v = y + (selS[j0 + s] ? zs[s] : 0.f);
                    const float th = tanhf(v);
                    rn[s] = th; ss += th * th;
                }
            }
#pragma unroll
            for (int off = 32; off > 0; off >>= 1)
                ss += __shfl_down(ss, (unsigned)off);
            if ((tid & 63) == 0) red[tid >> 6] = ss;
            __syncthreads();
            if (tid == 0) {
                float a = 0.f;
#pragma unroll
                for (int i = 0; i < 8; ++i) a += red[i];
                s_norm = sqrtf(a) + 1e-6f;
            }
            __syncthreads();
            const float inv = 1.0f / s_norm;
            u16 o0[4], o1[4];
#pragma unroll
            for (int s = 0; s < 4; ++s) {
                const float v = rn[s] * inv;
                rn[s] = v;
                split2(v, o0[s], o1[s]);
            }
            ull p0, p1;
            __builtin_memcpy(&p0, o0, 8); __builtin_memcpy(&p1, o1, 8);
            const long long wslot = rot ? (long long)(t + 1) * SLOTU : 0ll;
            const long long rbase = (long long)b * REC + j0;
            cstore8u(rTu + wslot + rbase, p0);
            cstore8u(rTu + wslot + 131072 + rbase, p1);
            if (t == NSTEP - 1)
                *(float4*)&out[rbase] = make_float4(rn[0], rn[1], rn[2], rn[3]);
        }
        ++gen; gbar(bar, bid, gen);   // r ready for next step
    }
}

// ---------------------------------------------------------------------------
extern "C" void kernel_launch(void* const* d_in, const int* in_sizes, int n_in,
                              void* d_out, int out_size, void* d_ws, size_t ws_size,
                              hipStream_t stream)
{
    const float* x   = (const float*)d_in[0];   // [64][512][512]
    const float* Win = (const float*)d_in[1];   // [512][2048]
    const float* Wr  = (const float*)d_in[2];   // [2048][2048]
    float* out = (float*)d_out;                 // [64][2048]

    char* ws = (char*)d_ws;
    const size_t BAR = 8192;
    const size_t ZPB = (size_t)KC * NB * REC * sizeof(float);      // 4 MB
    const size_t SLOTB = (size_t)SLOTU * sizeof(u16);              // 512 KB
    const size_t YB  = (size_t)NSTEP * NB * REC * sizeof(u16);     // 128 MB
    const size_t needRot = BAR + ZPB + 513 * SLOTB + YB;           // ~401 MB
    const int rot = (ws_size >= needRot) ? 1 : 0;

    unsigned* bar = (unsigned*)ws;
    float* zpart  = (float*)(ws + BAR);
    u16*   rTu    = (u16*)(ws + BAR + ZPB);
    u16*   Ybf    = (u16*)(ws + BAR + ZPB + (rot ? 513 * SLOTB : SLOTB));

    static int smem_set = 0;
    if (!smem_set) {
        hipFuncSetAttribute((const void*)rnn_persistent,
                            hipFuncAttributeMaxDynamicSharedMemorySize, 151552);
        smem_set = 1;
    }
    hipMemsetAsync(bar, 0, BAR, stream);
    rnn_persistent<<<256, 512, 151552, stream>>>(x, Win, Wr, out, rTu, zpart, Ybf, bar, rot);
}

// Round 8
// 10585.805 us; speedup vs baseline: 1.0616x; 1.0616x over previous
//
#include <hip/hip_runtime.h>

#define NSTEP 512
#define EDIM  512
#define REC   2048
#define NB    64
#define KSEL  819
#define KC    8       // K chunks of 256 (kc = bid & 7)
#define ZCH   256     // K per block
#define AP    264     // padded k-stride (u16) for LDS tiles
#define CSTR  16896   // 64*AP: component stride inside LDS tiles

typedef unsigned short u16;
typedef __bf16 bf16x8 __attribute__((ext_vector_type(8)));
typedef float  f32x4  __attribute__((ext_vector_type(4)));
typedef unsigned long long ull;

static __device__ __forceinline__ f32x4 mfma16(bf16x8 a, bf16x8 b, f32x4 c) {
    return __builtin_amdgcn_mfma_f32_16x16x32_bf16(a, b, c, 0, 0, 0);
}

// fp32 -> 2 bf16 components (hi, lo): ~17 mantissa bits
static __device__ __forceinline__ void split2(float v, u16& c0, u16& c1) {
    __bf16 b0 = (__bf16)v;
    __bf16 b1 = (__bf16)(v - (float)b0);
    c0 = __builtin_bit_cast(u16, b0);
    c1 = __builtin_bit_cast(u16, b1);
}

// ---- agent-scope (sc1) coherent helpers — compiler-tracked, no inline asm ----
static __device__ __forceinline__ void cstore4f(float* p, float v) {
    __hip_atomic_store((unsigned*)p, __float_as_uint(v), __ATOMIC_RELAXED, __HIP_MEMORY_SCOPE_AGENT);
}
static __device__ __forceinline__ float cload4f(const float* p) {
    unsigned u = __hip_atomic_load((const unsigned*)p, __ATOMIC_RELAXED, __HIP_MEMORY_SCOPE_AGENT);
    return __uint_as_float(u);
}
static __device__ __forceinline__ void cstore8u(void* p, ull v) {
    __hip_atomic_store((ull*)p, v, __ATOMIC_RELAXED, __HIP_MEMORY_SCOPE_AGENT);
}
static __device__ __forceinline__ ull cload8u(const void* p) {
    return __hip_atomic_load((const ull*)p, __ATOMIC_RELAXED, __HIP_MEMORY_SCOPE_AGENT);
}

// ---- two-level grid barrier (r3-r7 proven) ----
__device__ __forceinline__ void gbar(unsigned* bar, int bid, unsigned gen)
{
    __syncthreads();
    if (threadIdx.x == 0) {
        const int g = bid >> 4;
        unsigned v = __hip_atomic_fetch_add(&bar[g * 32], 1u,
                        __ATOMIC_RELAXED, __HIP_MEMORY_SCOPE_AGENT);
        if (v + 1u == gen * 16u)
            __hip_atomic_fetch_add(&bar[1024], 1u,
                        __ATOMIC_RELAXED, __HIP_MEMORY_SCOPE_AGENT);
        while (__hip_atomic_load(&bar[1024], __ATOMIC_RELAXED,
                        __HIP_MEMORY_SCOPE_AGENT) < gen * 16u)
            __builtin_amdgcn_s_sleep(1);
        __asm__ volatile("" ::: "memory");
    }
    __syncthreads();
}

// ---------------------------------------------------------------------------
// Persistent kernel: 256 blocks x 512 threads.
// Block (kc=bid&7, nc=bid>>3): GEMM tile cols [nc*64,+64), K [kc*256,+256).
// z accumulated by HW f32 atomics into ping-pong buffer zb[t&1] (512 KB),
// zeroed one step ahead. Blocks 0..63 run phase B (one batch row each):
// register-held keys, per-wave-private radix histograms.
// LDS (135168 B): WrSu 67584 | aSu 67584 (phase-B scratch aliases aSu;
// Y-precompute WiP/xP alias WrSu).
// ---------------------------------------------------------------------------
__global__ __launch_bounds__(512, 1)
void rnn_persistent(const float* __restrict__ x, const float* __restrict__ Wi,
                    const float* __restrict__ Wr, float* __restrict__ out,
                    u16* __restrict__ rTu, float* __restrict__ zb,
                    u16* __restrict__ Ybf, unsigned* __restrict__ bar)
{
    extern __shared__ __align__(16) char smem[];
    u16* WrSu = (u16*)smem;                         // + c*CSTR
    u16* aSu  = (u16*)(smem + 67584);               // + c*CSTR
    // Y-precompute views (alias WrS region)
    float* WiP = (float*)smem;                      // [32][128] 16 KB
    float* xP  = (float*)(smem + 16384);            // [32][64]   8 KB
    // phase-B views (alias aS region)
    unsigned*      kS    = (unsigned*)(smem + 67584);            // [2048] 8 KB
    unsigned char* selS  = (unsigned char*)(smem + 67584 + 8192);// 2 KB
    unsigned*      hist  = (unsigned*)(smem + 67584 + 10240);    // [8][256] 8 KB
    u16*           rsp0  = (u16*)(smem + 67584 + 18432);         // [2048] 4 KB
    u16*           rsp1  = (u16*)(smem + 67584 + 22528);         // [2048] 4 KB
    __shared__ unsigned s_byte, s_newrem, s_cnteq;
    __shared__ float red[8];
    __shared__ float s_norm;

    const int bid = blockIdx.x;
    const int tid = threadIdx.x;
    const int kc = bid & 7, nc = bid >> 3;
    const int n0 = nc * 64, kcbase = kc * ZCH;
    const int wid = tid >> 6, lane = tid & 63;
    const int q = lane >> 4, l16 = lane & 15;
    const int Moff = (wid & 3) * 16, Npair = wid >> 2;
    unsigned gen = 0;

    // ================= Y precompute: Y[t][b][j] = (x_t @ Wi) bf16 ===========
    {
        const int t0 = bid * 2;
        const int tr4 = (tid >> 5) * 4;
        const int tc4 = (tid & 31) * 4;
        for (int nc2 = 0; nc2 < 16; ++nc2) {
            const int n0y = nc2 * 128;
            f32x4 acc[2][4];
#pragma unroll
            for (int h = 0; h < 2; ++h)
#pragma unroll
                for (int i = 0; i < 4; ++i) acc[h][i] = (f32x4){0,0,0,0};
            for (int kr = 0; kr < 16; ++kr) {
                const int k0y = kr * 32;
                __syncthreads();
                {
                    const int col4 = (tid & 31) * 4, row = tid >> 5;
                    *(float4*)&WiP[row * 128 + col4] =
                        *(const float4*)(Wi + (long long)(k0y + row) * REC + n0y + col4);
                    *(float4*)&WiP[(row + 16) * 128 + col4] =
                        *(const float4*)(Wi + (long long)(k0y + row + 16) * REC + n0y + col4);
                }
                for (int h = 0; h < 2; ++h) {
                    __syncthreads();
                    {
                        const int b = tid & 63, e4 = (tid >> 6) * 4;
                        const float4 v = *(const float4*)(x + ((long long)b * NSTEP + (t0 + h)) * EDIM + k0y + e4);
                        xP[(e4    ) * 64 + b] = v.x;
                        xP[(e4 + 1) * 64 + b] = v.y;
                        xP[(e4 + 2) * 64 + b] = v.z;
                        xP[(e4 + 3) * 64 + b] = v.w;
                    }
                    __syncthreads();
#pragma unroll 8
                    for (int kk = 0; kk < 32; ++kk) {
                        const float4 af = *(const float4*)&xP[kk * 64 + tr4];
                        const float4 bf = *(const float4*)&WiP[kk * 128 + tc4];
                        const float av[4] = {af.x, af.y, af.z, af.w};
#pragma unroll
                        for (int i = 0; i < 4; ++i) {
                            acc[h][i].x += av[i] * bf.x;
                            acc[h][i].y += av[i] * bf.y;
                            acc[h][i].z += av[i] * bf.z;
                            acc[h][i].w += av[i] * bf.w;
                        }
                    }
                }
            }
#pragma unroll
            for (int h = 0; h < 2; ++h)
#pragma unroll
                for (int i = 0; i < 4; ++i) {
                    const long long yrow = (long long)(t0 + h) * 64 + tr4 + i;
                    u16 o[4];
                    o[0] = __builtin_bit_cast(u16, (__bf16)acc[h][i].x);
                    o[1] = __builtin_bit_cast(u16, (__bf16)acc[h][i].y);
                    o[2] = __builtin_bit_cast(u16, (__bf16)acc[h][i].z);
                    o[3] = __builtin_bit_cast(u16, (__bf16)acc[h][i].w);
                    ull pk; __builtin_memcpy(&pk, o, 8);
                    cstore8u(&Ybf[yrow * REC + n0y + tc4], pk);
                }
        }
    }
    // ---- init: zero r slot (512 KB) and zb[0] (512 KB) ----
    {
        const int g = bid * 512 + tid;                  // 0..131071
        if (g < 65536) cstore8u(rTu + (long long)g * 4, 0ull);
        cstore4f(zb + g, 0.f);                          // zb[0] fully zeroed
    }
    ++gen; gbar(bar, bid, gen);

    // ================= one-time: stage + split Wr tile into LDS =============
    {
        for (int it = 0; it < 32; ++it) {
            const int row = it * 8 + wid;
            const int col = lane;
            const float v = Wr[(long long)(kcbase + row) * REC + n0 + col];
            u16 s0, s1; split2(v, s0, s1);
            const int base = col * AP + row;
            WrSu[base] = s0;
            WrSu[CSTR + base] = s1;
        }
        __syncthreads();
    }

    // ================= main recurrence ======================================
    const int hw = tid >> 5, hl = tid & 31;
    for (int t = 0; t < NSTEP; ++t) {
        float* zcur = zb + (size_t)(t & 1) * 131072;
        float* znxt = zb + (size_t)((t + 1) & 1) * 131072;
        // ---- stage aS: 2 comps x 64 b x 256 k, sc1 8B (r5-proven) ----
        {
            ull va[8], vbv[8];
#pragma unroll
            for (int i = 0; i < 8; ++i) {
                const int c = i >> 2;
                const int b = (i & 3) * 16 + hw;
                const u16* src = rTu + (long long)c * 131072 + (long long)b * REC + kcbase + hl * 8;
                va[i] = cload8u(src);
                vbv[i] = cload8u(src + 4);
            }
#pragma unroll
            for (int i = 0; i < 8; ++i) {
                const int c = i >> 2;
                const int b = (i & 3) * 16 + hw;
                u16* dst = aSu + c * CSTR + b * AP + hl * 8;
                *(ull*)dst = va[i];
                *(ull*)(dst + 4) = vbv[i];
            }
        }
        // zero next-parity z buffer (consumed at t+1, after bar2 of t)
        cstore4f(znxt + bid * 512 + tid, 0.f);
        __syncthreads();

        // ---- z tile: 3-pass split-bf16 MFMA, K=256 ----
        f32x4 acc0 = {0,0,0,0}, acc1 = {0,0,0,0};
#pragma unroll
        for (int ks = 0; ks < 8; ++ks) {
            const int kk = ks * 32 + q * 8;
            const u16* ap = aSu + (Moff + l16) * AP + kk;
            bf16x8 A0 = *(const bf16x8*)(ap);
            bf16x8 A1 = *(const bf16x8*)(ap + CSTR);
            const u16* bp0 = WrSu + (Npair * 32 + l16) * AP + kk;
            bf16x8 B00 = *(const bf16x8*)(bp0);
            bf16x8 B01 = *(const bf16x8*)(bp0 + CSTR);
            const u16* bp1 = bp0 + 16 * AP;
            bf16x8 B10 = *(const bf16x8*)(bp1);
            bf16x8 B11 = *(const bf16x8*)(bp1 + CSTR);
            acc0 = mfma16(A0, B00, acc0);
            acc1 = mfma16(A0, B10, acc1);
            acc0 = mfma16(A0, B01, acc0);
            acc1 = mfma16(A0, B11, acc1);
            acc0 = mfma16(A1, B00, acc0);
            acc1 = mfma16(A1, B10, acc1);
        }
        // ---- accumulate into z via HW f32 atomics (D: row=Moff+q*4+i) ----
        {
            const int colA = n0 + Npair * 32 + l16;
#pragma unroll
            for (int i = 0; i < 4; ++i) {
                float* zp = zcur + (long long)(Moff + q * 4 + i) * REC + colA;
                unsafeAtomicAdd(zp,      ((float*)&acc0)[i]);
                unsafeAtomicAdd(zp + 16, ((float*)&acc1)[i]);
            }
        }
        ++gen; gbar(bar, bid, gen);   // z complete & visible

        // ================= phase B: blocks 0..63, one batch row each ========
        if (bid < NB) {
            const int b = bid;
            // z row: interleaved j = tid + 512*s (stride-1 coalesced sc1)
            float zs[4];
            unsigned kv[4];
#pragma unroll
            for (int s = 0; s < 4; ++s) {
                const int j = tid + 512 * s;
                const float v = cload4f(zcur + (long long)b * REC + j);
                zs[s] = v;
                const unsigned u = __float_as_uint(v);
                const unsigned k = (u & 0x80000000u) ? ~u : (u | 0x80000000u);
                kv[s] = k;
                kS[j] = k;                      // for rare tie path only
            }
            // ---- 4-round radix select, per-wave-private histograms ----
            unsigned* hw_ = hist + wid * 256;
            unsigned prefix = 0, remaining = KSEL;
            for (int byte = 3; byte >= 0; --byte) {
                {   // zero own copy (wave-private, no block sync needed)
                    uint4 zz = {0u, 0u, 0u, 0u};
                    *(uint4*)&hw_[lane * 4] = zz;
                }
                const int shift = byte * 8;
                const unsigned pmask = (byte == 3) ? 0u : (0xFFFFFFFFu << (shift + 8));
#pragma unroll
                for (int s = 0; s < 4; ++s) {
                    if ((kv[s] & pmask) == prefix)
                        atomicAdd(&hw_[(kv[s] >> shift) & 255u], 1u);
                }
                __syncthreads();
                if (tid < 64) {   // wave 0: combine 8 copies + suffix scan
                    unsigned c0 = 0, c1 = 0, c2 = 0, c3 = 0;
#pragma unroll
                    for (int w = 0; w < 8; ++w) {
                        const uint4 hv = *(const uint4*)&hist[w * 256 + tid * 4];
                        c0 += hv.x; c1 += hv.y; c2 += hv.z; c3 += hv.w;
                    }
                    const unsigned tot = c0 + c1 + c2 + c3;
                    unsigned suf = tot;
#pragma unroll
                    for (int st = 1; st < 64; st <<= 1) {
                        unsigned o = __shfl_down(suf, (unsigned)st);
                        if (tid + st >= 64) o = 0u;
                        suf += o;
                    }
                    unsigned S[5];
                    S[0] = suf; S[1] = suf - c0; S[2] = suf - c0 - c1;
                    S[3] = suf - c0 - c1 - c2; S[4] = suf - tot;
                    const unsigned cc[4] = {c0, c1, c2, c3};
#pragma unroll
                    for (int qq = 0; qq < 4; ++qq) {
                        if (S[qq] >= remaining && S[qq + 1] < remaining) {
                            s_byte = (unsigned)(tid * 4 + qq);
                            s_newrem = remaining - S[qq + 1];
                            s_cnteq = cc[qq];
                        }
                    }
                }
                __syncthreads();
                prefix |= (s_byte << shift);
                remaining = s_newrem;
            }
            const unsigned T = prefix;
            const unsigned need = remaining;
            const unsigned cnteq = s_cnteq;
            unsigned char sel[4];
            if (need == cnteq) {
#pragma unroll
                for (int s = 0; s < 4; ++s)
                    sel[s] = (kv[s] >= T) ? 1 : 0;
            } else {
                // tie at threshold (step 0: all-zero z). Serial, rare.
                if (tid == 0) {
                    unsigned rem = need;
                    for (int j = 0; j < REC; ++j) {
                        const unsigned k = kS[j];
                        unsigned char sl = 0;
                        if (k > T) sl = 1;
                        else if (k == T && rem > 0u) { sl = 1; --rem; }
                        selS[j] = sl;
                    }
                }
                __syncthreads();
#pragma unroll
                for (int s = 0; s < 4; ++s) sel[s] = selS[tid + 512 * s];
            }
            // ---- r_new = tanh(y + masked z), row-normalize ----
            float rn[4]; float ss = 0.f;
#pragma unroll
            for (int s = 0; s < 4; ++s) {
                const int j = tid + 512 * s;
                const float y = __uint_as_float(
                    ((unsigned)Ybf[((long long)t * 64 + b) * REC + j]) << 16);
                const float v = y + (sel[s] ? zs[s] : 0.f);
                const float th = tanhf(v);
                rn[s] = th; ss += th * th;
            }
#pragma unroll
            for (int off = 32; off > 0; off >>= 1)
                ss += __shfl_down(ss, (unsigned)off);
            if (lane == 0) red[wid] = ss;
            __syncthreads();
            if (tid == 0) {
                float a = 0.f;
#pragma unroll
                for (int i = 0; i < 8; ++i) a += red[i];
                s_norm = sqrtf(a) + 1e-6f;
            }
            __syncthreads();
            const float inv = 1.0f / s_norm;
#pragma unroll
            for (int s = 0; s < 4; ++s) {
                const int j = tid + 512 * s;
                const float v = rn[s] * inv;
                u16 c0, c1; split2(v, c0, c1);
                rsp0[j] = c0; rsp1[j] = c1;
                if (t == NSTEP - 1) out[(long long)b * REC + j] = v;
            }
            __syncthreads();
            {   // coalesced 8B sc1 stores of the split state
                const int i4 = tid * 4;
                cstore8u(rTu + (long long)b * REC + i4,          *(ull*)&rsp0[i4]);
                cstore8u(rTu + 131072 + (long long)b * REC + i4, *(ull*)&rsp1[i4]);
            }
        }
        ++gen; gbar(bar, bid, gen);   // r ready for next step
    }
}

// ---------------------------------------------------------------------------
extern "C" void kernel_launch(void* const* d_in, const int* in_sizes, int n_in,
                              void* d_out, int out_size, void* d_ws, size_t ws_size,
                              hipStream_t stream)
{
    const float* x   = (const float*)d_in[0];   // [64][512][512]
    const float* Win = (const float*)d_in[1];   // [512][2048]
    const float* Wr  = (const float*)d_in[2];   // [2048][2048]
    float* out = (float*)d_out;                 // [64][2048]

    char* ws = (char*)d_ws;
    const size_t BAR = 8192;
    unsigned* bar = (unsigned*)ws;
    float* zb  = (float*)(ws + BAR);                        // 2 x 512 KB ping-pong
    u16*   rTu = (u16*)(ws + BAR + 2 * 524288);             // 512 KB split state
    u16*   Ybf = (u16*)(ws + BAR + 2 * 524288 + 524288);    // 128 MB

    static int smem_set = 0;
    if (!smem_set) {
        hipFuncSetAttribute((const void*)rnn_persistent,
                            hipFuncAttributeMaxDynamicSharedMemorySize, 135168);
        smem_set = 1;
    }
    hipMemsetAsync(bar, 0, BAR, stream);
    rnn_persistent<<<256, 512, 135168, stream>>>(x, Win, Wr, out, rTu, zb, Ybf, bar);
}

// Round 9
// 8741.717 us; speedup vs baseline: 1.2856x; 1.2110x over previous
//
#include <hip/hip_runtime.h>

#define NSTEP 512
#define EDIM  512
#define REC   2048
#define NB    64
#define KSEL  819
#define KC    8       // K chunks of 256 (kc = bid & 7)
#define ZCH   256     // K per block
#define AP    264     // padded k-stride (u16) for LDS tiles
#define CSTR  16896   // 64*AP: component stride inside LDS tiles

typedef unsigned short u16;
typedef __bf16 bf16x8 __attribute__((ext_vector_type(8)));
typedef float  f32x4  __attribute__((ext_vector_type(4)));
typedef unsigned long long ull;

static __device__ __forceinline__ f32x4 mfma16(bf16x8 a, bf16x8 b, f32x4 c) {
    return __builtin_amdgcn_mfma_f32_16x16x32_bf16(a, b, c, 0, 0, 0);
}

// fp32 -> 2 bf16 components (hi, lo): ~17 mantissa bits
static __device__ __forceinline__ void split2(float v, u16& c0, u16& c1) {
    __bf16 b0 = (__bf16)v;
    __bf16 b1 = (__bf16)(v - (float)b0);
    c0 = __builtin_bit_cast(u16, b0);
    c1 = __builtin_bit_cast(u16, b1);
}

// ---- agent-scope (sc1) coherent helpers — compiler-tracked ----
static __device__ __forceinline__ void cstore4f(float* p, float v) {
    __hip_atomic_store((unsigned*)p, __float_as_uint(v), __ATOMIC_RELAXED, __HIP_MEMORY_SCOPE_AGENT);
}
static __device__ __forceinline__ void cstore4u(unsigned* p, unsigned v) {
    __hip_atomic_store(p, v, __ATOMIC_RELAXED, __HIP_MEMORY_SCOPE_AGENT);
}
static __device__ __forceinline__ unsigned cload4u(const unsigned* p) {
    return __hip_atomic_load(p, __ATOMIC_RELAXED, __HIP_MEMORY_SCOPE_AGENT);
}
static __device__ __forceinline__ void cstore8u(void* p, ull v) {
    __hip_atomic_store((ull*)p, v, __ATOMIC_RELAXED, __HIP_MEMORY_SCOPE_AGENT);
}
static __device__ __forceinline__ ull cload8u(const void* p) {
    return __hip_atomic_load((const ull*)p, __ATOMIC_RELAXED, __HIP_MEMORY_SCOPE_AGENT);
}
static __device__ __forceinline__ float2 cload8f(const float* p) {
    ull u = cload8u(p);
    float2 v; __builtin_memcpy(&v, &u, 8);
    return v;
}

// ---- store-slot hierarchical barrier (no RMW, bounded poll contention) ----
// bar layout (uints): arrive g*32+i (i<16, one 128B line/group);
// root slots 512..527; release flags 1024+g*32 (one line each).
__device__ __forceinline__ void gbar(unsigned* bar, int bid, unsigned gen)
{
    __syncthreads();                    // drains all block stores (vmcnt)
    if (threadIdx.x == 0) {
        const int g = bid >> 4, idx = bid & 15;
        cstore4u(&bar[g * 32 + idx], gen);            // arrive (fire & forget)
        if (idx == 0) {                               // group leader
            const ull* slots = (const ull*)&bar[g * 32];
            for (;;) {
                bool ok = true;
#pragma unroll
                for (int i = 0; i < 8; ++i) {
                    const ull v = cload8u(&slots[i]);
                    if ((unsigned)v < gen || (unsigned)(v >> 32) < gen) ok = false;
                }
                if (ok) break;
                __builtin_amdgcn_s_sleep(1);
            }
            cstore4u(&bar[512 + g], gen);             // post to root
            if (bid == 0) {                           // root leader
                const ull* rs = (const ull*)&bar[512];
                for (;;) {
                    bool ok = true;
#pragma unroll
                    for (int i = 0; i < 8; ++i) {
                        const ull v = cload8u(&rs[i]);
                        if ((unsigned)v < gen || (unsigned)(v >> 32) < gen) ok = false;
                    }
                    if (ok) break;
                    __builtin_amdgcn_s_sleep(1);
                }
#pragma unroll
                for (int gg = 0; gg < 16; ++gg)       // broadcast release
                    cstore4u(&bar[1024 + gg * 32], gen);
            }
        }
        while (cload4u(&bar[1024 + g * 32]) < gen)    // ≤16 pollers per line
            __builtin_amdgcn_s_sleep(1);
        __asm__ volatile("" ::: "memory");
    }
    __syncthreads();
}

// ---------------------------------------------------------------------------
// Persistent kernel: 256 blocks x 512 threads (structure as r8).
// LDS (135168 B): WrSu 67584 | aSu 67584; phase-B scratch aliases aSu;
// Y-precompute WiP/xP alias WrSu.
// ---------------------------------------------------------------------------
__global__ __launch_bounds__(512, 1)
void rnn_persistent(const float* __restrict__ x, const float* __restrict__ Wi,
                    const float* __restrict__ Wr, float* __restrict__ out,
                    u16* __restrict__ rTu, float* __restrict__ zb,
                    u16* __restrict__ Ybf, unsigned* __restrict__ bar)
{
    extern __shared__ __align__(16) char smem[];
    u16* WrSu = (u16*)smem;                         // + c*CSTR
    u16* aSu  = (u16*)(smem + 67584);               // + c*CSTR
    // Y-precompute views (alias WrS region)
    float* WiP = (float*)smem;                      // [32][128] 16 KB
    float* xP  = (float*)(smem + 16384);            // [32][64]   8 KB
    // phase-B views (alias aS region)
    unsigned*      kS    = (unsigned*)(smem + 67584);            // [2048] 8 KB
    unsigned char* selS  = (unsigned char*)(smem + 67584 + 8192);// 2 KB
    unsigned*      hist  = (unsigned*)(smem + 67584 + 10240);    // [8][256] 8 KB
    __shared__ unsigned s_byte, s_newrem, s_cnteq;
    __shared__ float red[8];
    __shared__ float s_norm;

    const int bid = blockIdx.x;
    const int tid = threadIdx.x;
    const int kc = bid & 7, nc = bid >> 3;
    const int n0 = nc * 64, kcbase = kc * ZCH;
    const int wid = tid >> 6, lane = tid & 63;
    const int q = lane >> 4, l16 = lane & 15;
    const int Moff = (wid & 3) * 16, Npair = wid >> 2;
    unsigned gen = 0;

    // ================= Y precompute: Y[t][b][j] = (x_t @ Wi) bf16 ===========
    {
        const int t0 = bid * 2;
        const int tr4 = (tid >> 5) * 4;
        const int tc4 = (tid & 31) * 4;
        for (int nc2 = 0; nc2 < 16; ++nc2) {
            const int n0y = nc2 * 128;
            f32x4 acc[2][4];
#pragma unroll
            for (int h = 0; h < 2; ++h)
#pragma unroll
                for (int i = 0; i < 4; ++i) acc[h][i] = (f32x4){0,0,0,0};
            for (int kr = 0; kr < 16; ++kr) {
                const int k0y = kr * 32;
                __syncthreads();
                {
                    const int col4 = (tid & 31) * 4, row = tid >> 5;
                    *(float4*)&WiP[row * 128 + col4] =
                        *(const float4*)(Wi + (long long)(k0y + row) * REC + n0y + col4);
                    *(float4*)&WiP[(row + 16) * 128 + col4] =
                        *(const float4*)(Wi + (long long)(k0y + row + 16) * REC + n0y + col4);
                }
                for (int h = 0; h < 2; ++h) {
                    __syncthreads();
                    {
                        const int b = tid & 63, e4 = (tid >> 6) * 4;
                        const float4 v = *(const float4*)(x + ((long long)b * NSTEP + (t0 + h)) * EDIM + k0y + e4);
                        xP[(e4    ) * 64 + b] = v.x;
                        xP[(e4 + 1) * 64 + b] = v.y;
                        xP[(e4 + 2) * 64 + b] = v.z;
                        xP[(e4 + 3) * 64 + b] = v.w;
                    }
                    __syncthreads();
#pragma unroll 8
                    for (int kk = 0; kk < 32; ++kk) {
                        const float4 af = *(const float4*)&xP[kk * 64 + tr4];
                        const float4 bf = *(const float4*)&WiP[kk * 128 + tc4];
                        const float av[4] = {af.x, af.y, af.z, af.w};
#pragma unroll
                        for (int i = 0; i < 4; ++i) {
                            acc[h][i].x += av[i] * bf.x;
                            acc[h][i].y += av[i] * bf.y;
                            acc[h][i].z += av[i] * bf.z;
                            acc[h][i].w += av[i] * bf.w;
                        }
                    }
                }
            }
#pragma unroll
            for (int h = 0; h < 2; ++h)
#pragma unroll
                for (int i = 0; i < 4; ++i) {
                    const long long yrow = (long long)(t0 + h) * 64 + tr4 + i;
                    u16 o[4];
                    o[0] = __builtin_bit_cast(u16, (__bf16)acc[h][i].x);
                    o[1] = __builtin_bit_cast(u16, (__bf16)acc[h][i].y);
                    o[2] = __builtin_bit_cast(u16, (__bf16)acc[h][i].z);
                    o[3] = __builtin_bit_cast(u16, (__bf16)acc[h][i].w);
                    ull pk; __builtin_memcpy(&pk, o, 8);
                    cstore8u(&Ybf[yrow * REC + n0y + tc4], pk);
                }
        }
    }
    // ---- init: zero r slot (512 KB) and zb[0] (512 KB) ----
    {
        const int g = bid * 512 + tid;                  // 0..131071
        if (g < 65536) cstore8u(rTu + (long long)g * 4, 0ull);
        cstore4f(zb + g, 0.f);
    }
    ++gen; gbar(bar, bid, gen);

    // ================= one-time: stage + split Wr tile into LDS =============
    {
        for (int it = 0; it < 32; ++it) {
            const int row = it * 8 + wid;
            const int col = lane;
            const float v = Wr[(long long)(kcbase + row) * REC + n0 + col];
            u16 s0, s1; split2(v, s0, s1);
            const int base = col * AP + row;
            WrSu[base] = s0;
            WrSu[CSTR + base] = s1;
        }
        __syncthreads();
    }

    // ================= main recurrence ======================================
    const int hw = tid >> 5, hl = tid & 31;
    for (int t = 0; t < NSTEP; ++t) {
        float* zcur = zb + (size_t)(t & 1) * 131072;
        float* znxt = zb + (size_t)((t + 1) & 1) * 131072;
        // zero next-parity z (early, hides latency)
        cstore4f(znxt + bid * 512 + tid, 0.f);
        // ---- stage aS: 2 comps x 64 b x 256 k, sc1 8B ----
        {
            ull va[8], vbv[8];
#pragma unroll
            for (int i = 0; i < 8; ++i) {
                const int c = i >> 2;
                const int b = (i & 3) * 16 + hw;
                const u16* src = rTu + (long long)c * 131072 + (long long)b * REC + kcbase + hl * 8;
                va[i] = cload8u(src);
                vbv[i] = cload8u(src + 4);
            }
#pragma unroll
            for (int i = 0; i < 8; ++i) {
                const int c = i >> 2;
                const int b = (i & 3) * 16 + hw;
                u16* dst = aSu + c * CSTR + b * AP + hl * 8;
                *(ull*)dst = va[i];
                *(ull*)(dst + 4) = vbv[i];
            }
        }
        __syncthreads();

        // ---- z tile: 3-pass split-bf16 MFMA, K=256 ----
        f32x4 acc0 = {0,0,0,0}, acc1 = {0,0,0,0};
#pragma unroll
        for (int ks = 0; ks < 8; ++ks) {
            const int kk = ks * 32 + q * 8;
            const u16* ap = aSu + (Moff + l16) * AP + kk;
            bf16x8 A0 = *(const bf16x8*)(ap);
            bf16x8 A1 = *(const bf16x8*)(ap + CSTR);
            const u16* bp0 = WrSu + (Npair * 32 + l16) * AP + kk;
            bf16x8 B00 = *(const bf16x8*)(bp0);
            bf16x8 B01 = *(const bf16x8*)(bp0 + CSTR);
            const u16* bp1 = bp0 + 16 * AP;
            bf16x8 B10 = *(const bf16x8*)(bp1);
            bf16x8 B11 = *(const bf16x8*)(bp1 + CSTR);
            acc0 = mfma16(A0, B00, acc0);
            acc1 = mfma16(A0, B10, acc1);
            acc0 = mfma16(A0, B01, acc0);
            acc1 = mfma16(A0, B11, acc1);
            acc0 = mfma16(A1, B00, acc0);
            acc1 = mfma16(A1, B10, acc1);
        }
        // ---- accumulate into z via HW f32 atomics ----
        {
            const int colA = n0 + Npair * 32 + l16;
#pragma unroll
            for (int i = 0; i < 4; ++i) {
                float* zp = zcur + (long long)(Moff + q * 4 + i) * REC + colA;
                unsafeAtomicAdd(zp,      ((float*)&acc0)[i]);
                unsafeAtomicAdd(zp + 16, ((float*)&acc1)[i]);
            }
        }
        ++gen; gbar(bar, bid, gen);   // z complete & visible

        // ================= phase B: blocks 0..63, one batch row each ========
        if (bid < NB) {
            const int b = bid;
            const int j0 = tid * 4;   // blocked indexing
            // z row: 2 x 8B sc1 loads; y: one 8B cached load (issued early)
            float zs[4];
            {
                const float2 u0 = cload8f(zcur + (long long)b * REC + j0);
                const float2 u1 = cload8f(zcur + (long long)b * REC + j0 + 2);
                zs[0] = u0.x; zs[1] = u0.y; zs[2] = u1.x; zs[3] = u1.y;
            }
            const ushort4 yv = *(const ushort4*)&Ybf[((long long)t * 64 + b) * REC + j0];
            unsigned kv[4];
#pragma unroll
            for (int s = 0; s < 4; ++s) {
                const unsigned u = __float_as_uint(zs[s]);
                kv[s] = (u & 0x80000000u) ? ~u : (u | 0x80000000u);
            }
            *(uint4*)&kS[j0] = *(uint4*)kv;     // for rare tie path
            // ---- radix select w/ early exit, per-wave-private histograms ----
            unsigned* hw_ = hist + wid * 256;
            unsigned prefix = 0, remaining = KSEL;
            int done = 0;
            for (int byte = 3; byte >= 0 && !done; --byte) {
                {
                    uint4 zz = {0u, 0u, 0u, 0u};
                    *(uint4*)&hw_[lane * 4] = zz;
                }
                const int shift = byte * 8;
                const unsigned pmask = (byte == 3) ? 0u : (0xFFFFFFFFu << (shift + 8));
#pragma unroll
                for (int s = 0; s < 4; ++s) {
                    if ((kv[s] & pmask) == prefix)
                        atomicAdd(&hw_[(kv[s] >> shift) & 255u], 1u);
                }
                __syncthreads();
                if (tid < 64) {   // wave 0: combine 8 copies + suffix scan
                    unsigned c0 = 0, c1 = 0, c2 = 0, c3 = 0;
#pragma unroll
                    for (int w = 0; w < 8; ++w) {
                        const uint4 hv = *(const uint4*)&hist[w * 256 + tid * 4];
                        c0 += hv.x; c1 += hv.y; c2 += hv.z; c3 += hv.w;
                    }
                    const unsigned tot = c0 + c1 + c2 + c3;
                    unsigned suf = tot;
#pragma unroll
                    for (int st = 1; st < 64; st <<= 1) {
                        unsigned o = __shfl_down(suf, (unsigned)st);
                        if (tid + st >= 64) o = 0u;
                        suf += o;
                    }
                    unsigned S[5];
                    S[0] = suf; S[1] = suf - c0; S[2] = suf - c0 - c1;
                    S[3] = suf - c0 - c1 - c2; S[4] = suf - tot;
                    const unsigned cc[4] = {c0, c1, c2, c3};
#pragma unroll
                    for (int qq = 0; qq < 4; ++qq) {
                        if (S[qq] >= remaining && S[qq + 1] < remaining) {
                            s_byte = (unsigned)(tid * 4 + qq);
                            s_newrem = remaining - S[qq + 1];
                            s_cnteq = cc[qq];
                        }
                    }
                }
                __syncthreads();
                prefix |= (s_byte << shift);
                remaining = s_newrem;
                if (remaining == s_cnteq) done = 1;  // whole bucket selected:
                                                      // sel <=> key >= prefix
            }
            unsigned char sel[4];
            if (done) {
#pragma unroll
                for (int s = 0; s < 4; ++s)
                    sel[s] = (kv[s] >= prefix) ? 1 : 0;
            } else {
                // tie at exact threshold (step 0: all-zero z). Serial, rare.
                if (tid == 0) {
                    unsigned rem = remaining;
                    const unsigned T = prefix;
                    for (int j = 0; j < REC; ++j) {
                        const unsigned k = kS[j];
                        unsigned char sl = 0;
                        if (k > T) sl = 1;
                        else if (k == T && rem > 0u) { sl = 1; --rem; }
                        selS[j] = sl;
                    }
                }
                __syncthreads();
#pragma unroll
                for (int s = 0; s < 4; ++s) sel[s] = selS[j0 + s];
            }
            // ---- r_new = tanh(y + masked z), row-normalize ----
            float rn[4]; float ss = 0.f;
            const u16 ya[4] = {yv.x, yv.y, yv.z, yv.w};
#pragma unroll
            for (int s = 0; s < 4; ++s) {
                const float y = __uint_as_float(((unsigned)ya[s]) << 16);
                const float v = y + (sel[s] ? zs[s] : 0.f);
                const float th = tanhf(v);
                rn[s] = th; ss += th * th;
            }
#pragma unroll
            for (int off = 32; off > 0; off >>= 1)
                ss += __shfl_down(ss, (unsigned)off);
            if (lane == 0) red[wid] = ss;
            __syncthreads();
            if (tid == 0) {
                float a = 0.f;
#pragma unroll
                for (int i = 0; i < 8; ++i) a += red[i];
                s_norm = sqrtf(a) + 1e-6f;
            }
            __syncthreads();
            const float inv = 1.0f / s_norm;
            u16 o0[4], o1[4];
#pragma unroll
            for (int s = 0; s < 4; ++s) {
                const float v = rn[s] * inv;
                split2(v, o0[s], o1[s]);
                if (t == NSTEP - 1) out[(long long)b * REC + j0 + s] = v;
            }
            ull p0, p1;
            __builtin_memcpy(&p0, o0, 8); __builtin_memcpy(&p1, o1, 8);
            cstore8u(rTu + (long long)b * REC + j0, p0);
            cstore8u(rTu + 131072 + (long long)b * REC + j0, p1);
        }
        ++gen; gbar(bar, bid, gen);   // r ready for next step
    }
}

// ---------------------------------------------------------------------------
extern "C" void kernel_launch(void* const* d_in, const int* in_sizes, int n_in,
                              void* d_out, int out_size, void* d_ws, size_t ws_size,
                              hipStream_t stream)
{
    const float* x   = (const float*)d_in[0];   // [64][512][512]
    const float* Win = (const float*)d_in[1];   // [512][2048]
    const float* Wr  = (const float*)d_in[2];   // [2048][2048]
    float* out = (float*)d_out;                 // [64][2048]

    char* ws = (char*)d_ws;
    const size_t BAR = 8192;
    unsigned* bar = (unsigned*)ws;
    float* zb  = (float*)(ws + BAR);                        // 2 x 512 KB ping-pong
    u16*   rTu = (u16*)(ws + BAR + 2 * 524288);             // 512 KB split state
    u16*   Ybf = (u16*)(ws + BAR + 2 * 524288 + 524288);    // 128 MB

    static int smem_set = 0;
    if (!smem_set) {
        hipFuncSetAttribute((const void*)rnn_persistent,
                            hipFuncAttributeMaxDynamicSharedMemorySize, 135168);
        smem_set = 1;
    }
    hipMemsetAsync(bar, 0, BAR, stream);
    rnn_persistent<<<256, 512, 135168, stream>>>(x, Win, Wr, out, rTu, zb, Ybf, bar);
}

// Round 10
// 7687.463 us; speedup vs baseline: 1.4619x; 1.1371x over previous
//
#include <hip/hip_runtime.h>

#define NSTEP 512
#define EDIM  512
#define REC   2048
#define NB    64
#define KSEL  819
#define KC    8       // K chunks of 256 (kc = bid & 7)
#define ZCH   256     // K per block
#define AP    264     // padded k-stride (u16) for LDS tiles
#define CSTR  16896   // 64*AP: component stride inside LDS tiles

typedef unsigned short u16;
typedef __bf16 bf16x8 __attribute__((ext_vector_type(8)));
typedef float  f32x4  __attribute__((ext_vector_type(4)));
typedef unsigned long long ull;

static __device__ __forceinline__ f32x4 mfma16(bf16x8 a, bf16x8 b, f32x4 c) {
    return __builtin_amdgcn_mfma_f32_16x16x32_bf16(a, b, c, 0, 0, 0);
}

// fp32 -> 2 bf16 components (hi, lo): ~17 mantissa bits
static __device__ __forceinline__ void split2(float v, u16& c0, u16& c1) {
    __bf16 b0 = (__bf16)v;
    __bf16 b1 = (__bf16)(v - (float)b0);
    c0 = __builtin_bit_cast(u16, b0);
    c1 = __builtin_bit_cast(u16, b1);
}

// ---- agent-scope (sc1) coherent helpers — compiler-tracked ----
static __device__ __forceinline__ void cstore4f(float* p, float v) {
    __hip_atomic_store((unsigned*)p, __float_as_uint(v), __ATOMIC_RELAXED, __HIP_MEMORY_SCOPE_AGENT);
}
static __device__ __forceinline__ void cstore4u(unsigned* p, unsigned v) {
    __hip_atomic_store(p, v, __ATOMIC_RELAXED, __HIP_MEMORY_SCOPE_AGENT);
}
static __device__ __forceinline__ unsigned cload4u(const unsigned* p) {
    return __hip_atomic_load(p, __ATOMIC_RELAXED, __HIP_MEMORY_SCOPE_AGENT);
}
static __device__ __forceinline__ void cstore8u(void* p, ull v) {
    __hip_atomic_store((ull*)p, v, __ATOMIC_RELAXED, __HIP_MEMORY_SCOPE_AGENT);
}
static __device__ __forceinline__ ull cload8u(const void* p) {
    return __hip_atomic_load((const ull*)p, __ATOMIC_RELAXED, __HIP_MEMORY_SCOPE_AGENT);
}
static __device__ __forceinline__ float2 cload8f(const float* p) {
    ull u = cload8u(p);
    float2 v; __builtin_memcpy(&v, &u, 8);
    return v;
}

// ---------------------------------------------------------------------------
// Single-level barriers. bar layout (uints):
//   arriveA[0..255]                       (all blocks arrive)
//   arriveB[512..575]                     (phase-B blocks arrive)
//   releaseA[1024 + g*32], g<16
//   releaseB[1536 + g*32], g<16
// Leader = block 0 wave 0: polls arrive slots in parallel (ballot), then
// stores 16 release lines. Monotonic gens, >= compares.
// ---------------------------------------------------------------------------
__device__ __forceinline__ void gbarA(unsigned* bar, int bid, int tid,
                                      unsigned gen, bool wait)
{
    __syncthreads();                               // drain block stores
    if (tid == 0) cstore4u(&bar[bid], gen);        // arrive
    if (bid == 0 && tid < 64) {                    // leader wave: parallel poll
        const ull* sl = (const ull*)bar;           // 128 ulls = 256 slots
        for (;;) {
            const ull v0 = cload8u(&sl[tid * 2]);
            const ull v1 = cload8u(&sl[tid * 2 + 1]);
            const bool ok = ((unsigned)v0 >= gen) && ((unsigned)(v0 >> 32) >= gen)
                         && ((unsigned)v1 >= gen) && ((unsigned)(v1 >> 32) >= gen);
            if (__all(ok)) break;
            __builtin_amdgcn_s_sleep(1);
        }
        if (tid < 16) cstore4u(&bar[1024 + tid * 32], gen);
    }
    if (wait) {
        if (tid == 0) {
            const int g = bid >> 4;
            while (cload4u(&bar[1024 + g * 32]) < gen)
                __builtin_amdgcn_s_sleep(1);
            __asm__ volatile("" ::: "memory");
        }
        __syncthreads();
    }
}

__device__ __forceinline__ void gbarB(unsigned* bar, int bid, int tid, unsigned gen)
{
    __syncthreads();                               // drain (phase-B r stores)
    if (bid < NB && tid == 0) cstore4u(&bar[512 + bid], gen);
    if (bid == 0 && tid < 64) {                    // leader wave: 1 slot/lane
        for (;;) {
            const unsigned v = cload4u(&bar[512 + tid]);
            if (__all(v >= gen)) break;
            __builtin_amdgcn_s_sleep(1);
        }
        if (tid < 16) cstore4u(&bar[1536 + tid * 32], gen);
    }
    if (tid == 0) {
        const int g = bid >> 4;
        while (cload4u(&bar[1536 + g * 32]) < gen)
            __builtin_amdgcn_s_sleep(1);
        __asm__ volatile("" ::: "memory");
    }
    __syncthreads();
}

// ---------------------------------------------------------------------------
// Persistent kernel: 256 blocks x 512 threads (structure as r9).
// LDS (135168 B): WrSu 67584 | aSu 67584; phase-B scratch aliases aSu;
// Y-precompute WiP/xP alias WrSu.
// ---------------------------------------------------------------------------
__global__ __launch_bounds__(512, 1)
void rnn_persistent(const float* __restrict__ x, const float* __restrict__ Wi,
                    const float* __restrict__ Wr, float* __restrict__ out,
                    u16* __restrict__ rTu, float* __restrict__ zb,
                    u16* __restrict__ Ybf, unsigned* __restrict__ bar)
{
    extern __shared__ __align__(16) char smem[];
    u16* WrSu = (u16*)smem;                         // + c*CSTR
    u16* aSu  = (u16*)(smem + 67584);               // + c*CSTR
    // Y-precompute views (alias WrS region)
    float* WiP = (float*)smem;                      // [32][128] 16 KB
    float* xP  = (float*)(smem + 16384);            // [32][64]   8 KB
    // phase-B views (alias aS region)
    unsigned*      kS    = (unsigned*)(smem + 67584);            // [2048] 8 KB
    unsigned char* selS  = (unsigned char*)(smem + 67584 + 8192);// 2 KB
    unsigned*      hist  = (unsigned*)(smem + 67584 + 10240);    // [8][256] 8 KB
    __shared__ unsigned s_byte, s_newrem, s_cnteq;
    __shared__ float red[8];

    const int bid = blockIdx.x;
    const int tid = threadIdx.x;
    const int kc = bid & 7, nc = bid >> 3;
    const int n0 = nc * 64, kcbase = kc * ZCH;
    const int wid = tid >> 6, lane = tid & 63;
    const int q = lane >> 4, l16 = lane & 15;
    const int Moff = (wid & 3) * 16, Npair = wid >> 2;
    const bool isB = (bid < NB);

    // ================= Y precompute: Y[t][b][j] = (x_t @ Wi) bf16 ===========
    {
        const int t0 = bid * 2;
        const int tr4 = (tid >> 5) * 4;
        const int tc4 = (tid & 31) * 4;
        for (int nc2 = 0; nc2 < 16; ++nc2) {
            const int n0y = nc2 * 128;
            f32x4 acc[2][4];
#pragma unroll
            for (int h = 0; h < 2; ++h)
#pragma unroll
                for (int i = 0; i < 4; ++i) acc[h][i] = (f32x4){0,0,0,0};
            for (int kr = 0; kr < 16; ++kr) {
                const int k0y = kr * 32;
                __syncthreads();
                {
                    const int col4 = (tid & 31) * 4, row = tid >> 5;
                    *(float4*)&WiP[row * 128 + col4] =
                        *(const float4*)(Wi + (long long)(k0y + row) * REC + n0y + col4);
                    *(float4*)&WiP[(row + 16) * 128 + col4] =
                        *(const float4*)(Wi + (long long)(k0y + row + 16) * REC + n0y + col4);
                }
                for (int h = 0; h < 2; ++h) {
                    __syncthreads();
                    {
                        const int b = tid & 63, e4 = (tid >> 6) * 4;
                        const float4 v = *(const float4*)(x + ((long long)b * NSTEP + (t0 + h)) * EDIM + k0y + e4);
                        xP[(e4    ) * 64 + b] = v.x;
                        xP[(e4 + 1) * 64 + b] = v.y;
                        xP[(e4 + 2) * 64 + b] = v.z;
                        xP[(e4 + 3) * 64 + b] = v.w;
                    }
                    __syncthreads();
#pragma unroll 8
                    for (int kk = 0; kk < 32; ++kk) {
                        const float4 af = *(const float4*)&xP[kk * 64 + tr4];
                        const float4 bf = *(const float4*)&WiP[kk * 128 + tc4];
                        const float av[4] = {af.x, af.y, af.z, af.w};
#pragma unroll
                        for (int i = 0; i < 4; ++i) {
                            acc[h][i].x += av[i] * bf.x;
                            acc[h][i].y += av[i] * bf.y;
                            acc[h][i].z += av[i] * bf.z;
                            acc[h][i].w += av[i] * bf.w;
                        }
                    }
                }
            }
#pragma unroll
            for (int h = 0; h < 2; ++h)
#pragma unroll
                for (int i = 0; i < 4; ++i) {
                    const long long yrow = (long long)(t0 + h) * 64 + tr4 + i;
                    u16 o[4];
                    o[0] = __builtin_bit_cast(u16, (__bf16)acc[h][i].x);
                    o[1] = __builtin_bit_cast(u16, (__bf16)acc[h][i].y);
                    o[2] = __builtin_bit_cast(u16, (__bf16)acc[h][i].z);
                    o[3] = __builtin_bit_cast(u16, (__bf16)acc[h][i].w);
                    ull pk; __builtin_memcpy(&pk, o, 8);
                    cstore8u(&Ybf[yrow * REC + n0y + tc4], pk);
                }
        }
    }
    // ---- init: zero r slot (512 KB) and zb[0] (512 KB) ----
    {
        const int g = bid * 512 + tid;                  // 0..131071
        if (g < 65536) cstore8u(rTu + (long long)g * 4, 0ull);
        cstore4f(zb + g, 0.f);
    }
    gbarA(bar, bid, tid, 1u, true);                    // init barrier (full)

    // ================= one-time: stage + split Wr tile into LDS =============
    {
        for (int it = 0; it < 32; ++it) {
            const int row = it * 8 + wid;
            const int col = lane;
            const float v = Wr[(long long)(kcbase + row) * REC + n0 + col];
            u16 s0, s1; split2(v, s0, s1);
            const int base = col * AP + row;
            WrSu[base] = s0;
            WrSu[CSTR + base] = s1;
        }
        __syncthreads();
    }

    // ================= main recurrence ======================================
    const int hw = tid >> 5, hl = tid & 31;
    for (int t = 0; t < NSTEP; ++t) {
        float* zcur = zb + (size_t)(t & 1) * 131072;
        float* znxt = zb + (size_t)((t + 1) & 1) * 131072;
        // zero next-parity z (early, hides latency)
        cstore4f(znxt + bid * 512 + tid, 0.f);
        // ---- stage aS: 2 comps x 64 b x 256 k, sc1 8B ----
        {
            ull va[8], vbv[8];
#pragma unroll
            for (int i = 0; i < 8; ++i) {
                const int c = i >> 2;
                const int b = (i & 3) * 16 + hw;
                const u16* src = rTu + (long long)c * 131072 + (long long)b * REC + kcbase + hl * 8;
                va[i] = cload8u(src);
                vbv[i] = cload8u(src + 4);
            }
#pragma unroll
            for (int i = 0; i < 8; ++i) {
                const int c = i >> 2;
                const int b = (i & 3) * 16 + hw;
                u16* dst = aSu + c * CSTR + b * AP + hl * 8;
                *(ull*)dst = va[i];
                *(ull*)(dst + 4) = vbv[i];
            }
        }
        __syncthreads();

        // ---- z tile: 3-pass split-bf16 MFMA, K=256 ----
        f32x4 acc0 = {0,0,0,0}, acc1 = {0,0,0,0};
#pragma unroll
        for (int ks = 0; ks < 8; ++ks) {
            const int kk = ks * 32 + q * 8;
            const u16* ap = aSu + (Moff + l16) * AP + kk;
            bf16x8 A0 = *(const bf16x8*)(ap);
            bf16x8 A1 = *(const bf16x8*)(ap + CSTR);
            const u16* bp0 = WrSu + (Npair * 32 + l16) * AP + kk;
            bf16x8 B00 = *(const bf16x8*)(bp0);
            bf16x8 B01 = *(const bf16x8*)(bp0 + CSTR);
            const u16* bp1 = bp0 + 16 * AP;
            bf16x8 B10 = *(const bf16x8*)(bp1);
            bf16x8 B11 = *(const bf16x8*)(bp1 + CSTR);
            acc0 = mfma16(A0, B00, acc0);
            acc1 = mfma16(A0, B10, acc1);
            acc0 = mfma16(A0, B01, acc0);
            acc1 = mfma16(A0, B11, acc1);
            acc0 = mfma16(A1, B00, acc0);
            acc1 = mfma16(A1, B10, acc1);
        }
        // ---- accumulate into z via HW f32 atomics ----
        {
            const int colA = n0 + Npair * 32 + l16;
#pragma unroll
            for (int i = 0; i < 4; ++i) {
                float* zp = zcur + (long long)(Moff + q * 4 + i) * REC + colA;
                unsafeAtomicAdd(zp,      ((float*)&acc0)[i]);
                unsafeAtomicAdd(zp + 16, ((float*)&acc1)[i]);
            }
        }
        // bar1: all arrive (drains atomics); only phase-B blocks wait
        gbarA(bar, bid, tid, (unsigned)(t + 2), isB);

        // ================= phase B: blocks 0..63, one batch row each ========
        if (isB) {
            const int b = bid;
            const int j0 = tid * 4;
            float zs[4];
            {
                const float2 u0 = cload8f(zcur + (long long)b * REC + j0);
                const float2 u1 = cload8f(zcur + (long long)b * REC + j0 + 2);
                zs[0] = u0.x; zs[1] = u0.y; zs[2] = u1.x; zs[3] = u1.y;
            }
            const ushort4 yv = *(const ushort4*)&Ybf[((long long)t * 64 + b) * REC + j0];
            unsigned kv[4];
#pragma unroll
            for (int s = 0; s < 4; ++s) {
                const unsigned u = __float_as_uint(zs[s]);
                kv[s] = (u & 0x80000000u) ? ~u : (u | 0x80000000u);
            }
            // ---- radix select w/ early exit, per-wave-private histograms ----
            unsigned* hw_ = hist + wid * 256;
            unsigned prefix = 0, remaining = KSEL;
            int done = 0;
            for (int byte = 3; byte >= 0 && !done; --byte) {
                {
                    uint4 zz = {0u, 0u, 0u, 0u};
                    *(uint4*)&hw_[lane * 4] = zz;
                }
                const int shift = byte * 8;
                const unsigned pmask = (byte == 3) ? 0u : (0xFFFFFFFFu << (shift + 8));
#pragma unroll
                for (int s = 0; s < 4; ++s) {
                    if ((kv[s] & pmask) == prefix)
                        atomicAdd(&hw_[(kv[s] >> shift) & 255u], 1u);
                }
                __syncthreads();
                if (tid < 64) {   // wave 0: combine 8 copies + suffix scan
                    unsigned c0 = 0, c1 = 0, c2 = 0, c3 = 0;
#pragma unroll
                    for (int w = 0; w < 8; ++w) {
                        const uint4 hv = *(const uint4*)&hist[w * 256 + tid * 4];
                        c0 += hv.x; c1 += hv.y; c2 += hv.z; c3 += hv.w;
                    }
                    const unsigned tot = c0 + c1 + c2 + c3;
                    unsigned suf = tot;
#pragma unroll
                    for (int st = 1; st < 64; st <<= 1) {
                        unsigned o = __shfl_down(suf, (unsigned)st);
                        if (tid + st >= 64) o = 0u;
                        suf += o;
                    }
                    unsigned S[5];
                    S[0] = suf; S[1] = suf - c0; S[2] = suf - c0 - c1;
                    S[3] = suf - c0 - c1 - c2; S[4] = suf - tot;
                    const unsigned cc[4] = {c0, c1, c2, c3};
#pragma unroll
                    for (int qq = 0; qq < 4; ++qq) {
                        if (S[qq] >= remaining && S[qq + 1] < remaining) {
                            s_byte = (unsigned)(tid * 4 + qq);
                            s_newrem = remaining - S[qq + 1];
                            s_cnteq = cc[qq];
                        }
                    }
                }
                __syncthreads();
                prefix |= (s_byte << shift);
                remaining = s_newrem;
                if (remaining == s_cnteq) done = 1;  // whole bucket selected
            }
            unsigned char sel[4];
            if (done) {
#pragma unroll
                for (int s = 0; s < 4; ++s)
                    sel[s] = (kv[s] >= prefix) ? 1 : 0;
            } else {
                // tie at exact threshold (step 0: all-zero z). Rare path.
                *(uint4*)&kS[j0] = *(uint4*)kv;
                __syncthreads();
                if (tid == 0) {
                    unsigned rem = remaining;
                    const unsigned T = prefix;
                    for (int j = 0; j < REC; ++j) {
                        const unsigned k = kS[j];
                        unsigned char sl = 0;
                        if (k > T) sl = 1;
                        else if (k == T && rem > 0u) { sl = 1; --rem; }
                        selS[j] = sl;
                    }
                }
                __syncthreads();
#pragma unroll
                for (int s = 0; s < 4; ++s) sel[s] = selS[j0 + s];
            }
            // ---- r_new = tanh(y + masked z), row-normalize ----
            float rn[4]; float ss = 0.f;
            const u16 ya[4] = {yv.x, yv.y, yv.z, yv.w};
#pragma unroll
            for (int s = 0; s < 4; ++s) {
                const float y = __uint_as_float(((unsigned)ya[s]) << 16);
                const float v = y + (sel[s] ? zs[s] : 0.f);
                const float th = tanhf(v);
                rn[s] = th; ss += th * th;
            }
#pragma unroll
            for (int off = 32; off > 0; off >>= 1)
                ss += __shfl_down(ss, (unsigned)off);
            if (lane == 0) red[wid] = ss;
            __syncthreads();
            float a = 0.f;
#pragma unroll
            for (int i = 0; i < 8; ++i) a += red[i];
            const float inv = 1.0f / (sqrtf(a) + 1e-6f);
            u16 o0[4], o1[4];
            float4 ov;
#pragma unroll
            for (int s = 0; s < 4; ++s) {
                const float v = rn[s] * inv;
                split2(v, o0[s], o1[s]);
                ((float*)&ov)[s] = v;
            }
            ull p0, p1;
            __builtin_memcpy(&p0, o0, 8); __builtin_memcpy(&p1, o1, 8);
            cstore8u(rTu + (long long)b * REC + j0, p0);
            cstore8u(rTu + 131072 + (long long)b * REC + j0, p1);
            if (t == NSTEP - 1)
                *(float4*)&out[(long long)b * REC + j0] = ov;
        }
        // bar2: phase-B blocks arrive; everyone waits (r ready)
        gbarB(bar, bid, tid, (unsigned)(t + 1));
    }
}

// ---------------------------------------------------------------------------
extern "C" void kernel_launch(void* const* d_in, const int* in_sizes, int n_in,
                              void* d_out, int out_size, void* d_ws, size_t ws_size,
                              hipStream_t stream)
{
    const float* x   = (const float*)d_in[0];   // [64][512][512]
    const float* Win = (const float*)d_in[1];   // [512][2048]
    const float* Wr  = (const float*)d_in[2];   // [2048][2048]
    float* out = (float*)d_out;                 // [64][2048]

    char* ws = (char*)d_ws;
    const size_t BAR = 8192;
    unsigned* bar = (unsigned*)ws;
    float* zb  = (float*)(ws + BAR);                        // 2 x 512 KB ping-pong
    u16*   rTu = (u16*)(ws + BAR + 2 * 524288);             // 512 KB split state
    u16*   Ybf = (u16*)(ws + BAR + 2 * 524288 + 524288);    // 128 MB

    static int smem_set = 0;
    if (!smem_set) {
        hipFuncSetAttribute((const void*)rnn_persistent,
                            hipFuncAttributeMaxDynamicSharedMemorySize, 135168);
        smem_set = 1;
    }
    hipMemsetAsync(bar, 0, BAR, stream);
    rnn_persistent<<<256, 512, 135168, stream>>>(x, Win, Wr, out, rTu, zb, Ybf, bar);
}